// Round 1
// baseline (2800.395 us; speedup 1.0000x reference)
//
#include <hip/hip_runtime.h>
#include <math.h>

#define DIM 128
#define NUM_RBF 64
#define K1DIM (DIM + NUM_RBF + DIM)   // 320
#define TILE 32
#define NTHREADS 256

__device__ __forceinline__ float sigmoidf_(float v) { return 1.0f / (1.0f + __expf(-v)); }
__device__ __forceinline__ float swishf_(float v)   { return v * sigmoidf_(v); }

// ---------------------------------------------------------------------------
// Pass 1: scatter edge_vec sums + counts into destination nodes (atomics).
// ---------------------------------------------------------------------------
__global__ void scatter_vec_kernel(const int* __restrict__ col,
                                   const float* __restrict__ edge_vec,
                                   float* __restrict__ vec_sum,
                                   float* __restrict__ counts, int E) {
    int e = blockIdx.x * blockDim.x + threadIdx.x;
    if (e >= E) return;
    int c = col[e];
    atomicAdd(&vec_sum[(size_t)c * 3 + 0], edge_vec[(size_t)e * 3 + 0]);
    atomicAdd(&vec_sum[(size_t)c * 3 + 1], edge_vec[(size_t)e * 3 + 1]);
    atomicAdd(&vec_sum[(size_t)c * 3 + 2], edge_vec[(size_t)e * 3 + 2]);
    atomicAdd(&counts[c], 1.0f);
}

// ---------------------------------------------------------------------------
// Shared GEMM tile body: acc[4][4] += A_tile[32 x 32*KTILES] @ B[K x 128]
// A in LDS (row stride LDA floats), B streamed global->LDS tile by tile.
// Thread t: eg = t>>5 (4 edges 4*eg..), cg = t&31 (4 cols 4*cg..).
// ---------------------------------------------------------------------------
template <int LDA, int KTILES>
__device__ __forceinline__ void gemm_tile(const float* __restrict__ sA,
                                          const float* __restrict__ Bg,
                                          float* __restrict__ sB,
                                          float acc[4][4], int eg, int cg, int tid) {
    for (int kt = 0; kt < KTILES; ++kt) {
        __syncthreads();
        const float4* Bg4 = (const float4*)(Bg + (size_t)kt * 32 * DIM);
        float4* sB4 = (float4*)sB;
#pragma unroll
        for (int i = 0; i < 4; ++i) sB4[i * NTHREADS + tid] = Bg4[i * NTHREADS + tid];
        __syncthreads();
#pragma unroll
        for (int k0 = 0; k0 < 32; k0 += 4) {
            float a[4][4];   // [edge][kk]
            float b[4][4];   // [kk][col]
#pragma unroll
            for (int i = 0; i < 4; ++i)
                *(float4*)a[i] = *(const float4*)(sA + (4 * eg + i) * LDA + kt * 32 + k0);
#pragma unroll
            for (int kk = 0; kk < 4; ++kk)
                *(float4*)b[kk] = *(const float4*)(sB + (k0 + kk) * DIM + 4 * cg);
#pragma unroll
            for (int kk = 0; kk < 4; ++kk)
#pragma unroll
                for (int i = 0; i < 4; ++i)
#pragma unroll
                    for (int j = 0; j < 4; ++j)
                        acc[i][j] = fmaf(a[i][kk], b[kk][j], acc[i][j]);
        }
    }
}

// ---------------------------------------------------------------------------
// Pass 2: fused edge pipeline.
//   gather [x[row] | edge_attr | x[col]] -> edge MLP (2 layers, swish)
//   -> cos_theta -> three-body MLP (2 layers, swish+sigmoid)
//   -> atomicAdd(m_ij * g_ijk) into aggr[col].
// ---------------------------------------------------------------------------
__global__ __launch_bounds__(NTHREADS, 2)
void edge_kernel(const float* __restrict__ x,
                 const int* __restrict__ edge_index,
                 const float* __restrict__ edge_attr,
                 const float* __restrict__ edge_vec,
                 const float* __restrict__ edge_length,
                 const float* __restrict__ e_w1, const float* __restrict__ e_b1,
                 const float* __restrict__ e_w2, const float* __restrict__ e_b2,
                 const float* __restrict__ t_w1, const float* __restrict__ t_b1,
                 const float* __restrict__ t_w2, const float* __restrict__ t_b2,
                 const float* __restrict__ vec_sum, const float* __restrict__ counts,
                 float* __restrict__ aggr, int E, int N) {
    __shared__ float s_in[TILE][K1DIM];   // 40 KB; later reused for m (16K) + h2 (16K)
    __shared__ float s_h1[TILE][DIM];     // 16 KB
    __shared__ float s_B[TILE][DIM];      // 16 KB weight staging
    __shared__ float s_cos[TILE];
    __shared__ int s_row[TILE], s_col[TILE];

    float (*s_m)[DIM]  = (float (*)[DIM])(&s_in[0][0]);
    float (*s_h2)[DIM] = (float (*)[DIM])(&s_in[0][0] + TILE * DIM);

    const int tid = threadIdx.x;
    const int eb  = blockIdx.x * TILE;
    const int lane = tid & 31, g8 = tid >> 5;
    const int eg = tid >> 5, cg = tid & 31;

    // --- stage edge meta ---
    if (tid < TILE)            s_row[tid] = edge_index[min(eb + tid, E - 1)];
    else if (tid < 2 * TILE)   s_col[tid - TILE] = edge_index[(size_t)E + min(eb + tid - TILE, E - 1)];
    __syncthreads();

    // --- gather A tile: [x[row] | attr | x[col]] ---
    for (int e = g8; e < TILE; e += 8) {
        int ge = min(eb + e, E - 1);
        int r = s_row[e], c = s_col[e];
        const float4* xr = (const float4*)(x + (size_t)r * DIM);
        const float4* xc = (const float4*)(x + (size_t)c * DIM);
        *(float4*)&s_in[e][4 * lane] = xr[lane];
        if (lane < NUM_RBF / 4)
            *(float4*)&s_in[e][DIM + 4 * lane] =
                ((const float4*)(edge_attr + (size_t)ge * NUM_RBF))[lane];
        *(float4*)&s_in[e][DIM + NUM_RBF + 4 * lane] = xc[lane];
    }

    // --- cos_theta per edge (needs pass-1 results) ---
    if (tid < TILE) {
        int e = tid;
        int ge = min(eb + e, E - 1);
        int c = s_col[e];
        float cnt = fmaxf(counts[c], 1.0f);
        float vx = vec_sum[(size_t)c * 3 + 0] / cnt;
        float vy = vec_sum[(size_t)c * 3 + 1] / cnt;
        float vz = vec_sum[(size_t)c * 3 + 2] / cnt;
        float ex = edge_vec[(size_t)ge * 3 + 0];
        float ey = edge_vec[(size_t)ge * 3 + 1];
        float ez = edge_vec[(size_t)ge * 3 + 2];
        float dot = ex * vx + ey * vy + ez * vz;
        float nrm = sqrtf(vx * vx + vy * vy + vz * vz);
        float denom = edge_length[ge] * (nrm + 1e-6f);
        float ct = dot / denom;
        s_cos[e] = fminf(1.0f, fmaxf(-1.0f, ct));
    }

    float acc[4][4];

    // --- layer 1: [32x320] @ e_w1 -> swish -> s_h1 ---
#pragma unroll
    for (int i = 0; i < 4; ++i)
#pragma unroll
        for (int j = 0; j < 4; ++j) acc[i][j] = 0.0f;
    gemm_tile<K1DIM, K1DIM / 32>(&s_in[0][0], e_w1, &s_B[0][0], acc, eg, cg, tid);
    {
        float4 bv = *(const float4*)(e_b1 + 4 * cg);
#pragma unroll
        for (int i = 0; i < 4; ++i) {
            float4 h;
            h.x = swishf_(acc[i][0] + bv.x);
            h.y = swishf_(acc[i][1] + bv.y);
            h.z = swishf_(acc[i][2] + bv.z);
            h.w = swishf_(acc[i][3] + bv.w);
            *(float4*)&s_h1[4 * eg + i][4 * cg] = h;
        }
    }

    // --- layer 2: [32x128] @ e_w2 -> swish -> s_m (overlays s_in) ---
#pragma unroll
    for (int i = 0; i < 4; ++i)
#pragma unroll
        for (int j = 0; j < 4; ++j) acc[i][j] = 0.0f;
    gemm_tile<DIM, DIM / 32>(&s_h1[0][0], e_w2, &s_B[0][0], acc, eg, cg, tid);
    {
        float4 bv = *(const float4*)(e_b2 + 4 * cg);
#pragma unroll
        for (int i = 0; i < 4; ++i) {
            float4 h;
            h.x = swishf_(acc[i][0] + bv.x);
            h.y = swishf_(acc[i][1] + bv.y);
            h.z = swishf_(acc[i][2] + bv.z);
            h.w = swishf_(acc[i][3] + bv.w);
            *(float4*)&s_m[4 * eg + i][4 * cg] = h;
        }
    }

    // --- layer 3: [m | cos] @ t_w1 -> swish -> s_h2 ---
#pragma unroll
    for (int i = 0; i < 4; ++i)
#pragma unroll
        for (int j = 0; j < 4; ++j) acc[i][j] = 0.0f;
    gemm_tile<DIM, DIM / 32>(&s_m[0][0], t_w1, &s_B[0][0], acc, eg, cg, tid);
    {
        float4 tr = *(const float4*)(t_w1 + (size_t)DIM * DIM + 4 * cg);  // row 128
        float4 bv = *(const float4*)(t_b1 + 4 * cg);
#pragma unroll
        for (int i = 0; i < 4; ++i) {
            float ct = s_cos[4 * eg + i];
            float4 h;
            h.x = swishf_(acc[i][0] + ct * tr.x + bv.x);
            h.y = swishf_(acc[i][1] + ct * tr.y + bv.y);
            h.z = swishf_(acc[i][2] + ct * tr.z + bv.z);
            h.w = swishf_(acc[i][3] + ct * tr.w + bv.w);
            *(float4*)&s_h2[4 * eg + i][4 * cg] = h;
        }
    }

    // --- layer 4: h2 @ t_w2 -> sigmoid -> gate m -> atomic scatter-add ---
#pragma unroll
    for (int i = 0; i < 4; ++i)
#pragma unroll
        for (int j = 0; j < 4; ++j) acc[i][j] = 0.0f;
    gemm_tile<DIM, DIM / 32>(&s_h2[0][0], t_w2, &s_B[0][0], acc, eg, cg, tid);
    {
        float4 bv = *(const float4*)(t_b2 + 4 * cg);
#pragma unroll
        for (int i = 0; i < 4; ++i) {
            int e = 4 * eg + i;
            if (eb + e < E) {
                float4 mv = *(float4*)&s_m[e][4 * cg];
                float g0 = sigmoidf_(acc[i][0] + bv.x);
                float g1 = sigmoidf_(acc[i][1] + bv.y);
                float g2 = sigmoidf_(acc[i][2] + bv.z);
                float g3 = sigmoidf_(acc[i][3] + bv.w);
                float* dst = aggr + (size_t)s_col[e] * DIM + 4 * cg;
                atomicAdd(dst + 0, mv.x * g0);
                atomicAdd(dst + 1, mv.y * g1);
                atomicAdd(dst + 2, mv.z * g2);
                atomicAdd(dst + 3, mv.w * g3);
            }
        }
    }
}

// ---------------------------------------------------------------------------
// Pass 3: node MLP on [x | aggr] with residual.
// ---------------------------------------------------------------------------
__global__ __launch_bounds__(NTHREADS, 2)
void node_kernel(const float* __restrict__ x, const float* __restrict__ aggr,
                 const float* __restrict__ n_w1, const float* __restrict__ n_b1,
                 const float* __restrict__ n_w2, const float* __restrict__ n_b2,
                 float* __restrict__ out, int N) {
    __shared__ float s_in[TILE][2 * DIM];  // 32 KB
    __shared__ float s_h1[TILE][DIM];      // 16 KB
    __shared__ float s_B[TILE][DIM];       // 16 KB

    const int tid = threadIdx.x;
    const int nb = blockIdx.x * TILE;
    const int lane = tid & 31, g8 = tid >> 5;
    const int eg = tid >> 5, cg = tid & 31;

    for (int n = g8; n < TILE; n += 8) {
        int gn = min(nb + n, N - 1);
        *(float4*)&s_in[n][4 * lane] = ((const float4*)(x + (size_t)gn * DIM))[lane];
        *(float4*)&s_in[n][DIM + 4 * lane] = ((const float4*)(aggr + (size_t)gn * DIM))[lane];
    }

    float acc[4][4];
#pragma unroll
    for (int i = 0; i < 4; ++i)
#pragma unroll
        for (int j = 0; j < 4; ++j) acc[i][j] = 0.0f;
    gemm_tile<2 * DIM, 2 * DIM / 32>(&s_in[0][0], n_w1, &s_B[0][0], acc, eg, cg, tid);
    {
        float4 bv = *(const float4*)(n_b1 + 4 * cg);
#pragma unroll
        for (int i = 0; i < 4; ++i) {
            float4 h;
            h.x = swishf_(acc[i][0] + bv.x);
            h.y = swishf_(acc[i][1] + bv.y);
            h.z = swishf_(acc[i][2] + bv.z);
            h.w = swishf_(acc[i][3] + bv.w);
            *(float4*)&s_h1[4 * eg + i][4 * cg] = h;
        }
    }

#pragma unroll
    for (int i = 0; i < 4; ++i)
#pragma unroll
        for (int j = 0; j < 4; ++j) acc[i][j] = 0.0f;
    gemm_tile<DIM, DIM / 32>(&s_h1[0][0], n_w2, &s_B[0][0], acc, eg, cg, tid);
    {
        float4 bv = *(const float4*)(n_b2 + 4 * cg);
#pragma unroll
        for (int i = 0; i < 4; ++i) {
            int n = nb + 4 * eg + i;
            if (n < N) {
                float4 xv = *(float4*)&s_in[4 * eg + i][4 * cg];
                float4 o;
                o.x = xv.x + swishf_(acc[i][0] + bv.x);
                o.y = xv.y + swishf_(acc[i][1] + bv.y);
                o.z = xv.z + swishf_(acc[i][2] + bv.z);
                o.w = xv.w + swishf_(acc[i][3] + bv.w);
                *(float4*)(out + (size_t)n * DIM + 4 * cg) = o;
            }
        }
    }
}

// ---------------------------------------------------------------------------
extern "C" void kernel_launch(void* const* d_in, const int* in_sizes, int n_in,
                              void* d_out, int out_size, void* d_ws, size_t ws_size,
                              hipStream_t stream) {
    const float* x           = (const float*)d_in[0];
    const int*   edge_index  = (const int*)d_in[1];
    const float* edge_attr   = (const float*)d_in[2];
    const float* edge_vec    = (const float*)d_in[3];
    const float* edge_length = (const float*)d_in[4];
    const float* e_w1 = (const float*)d_in[5];
    const float* e_b1 = (const float*)d_in[6];
    const float* e_w2 = (const float*)d_in[7];
    const float* e_b2 = (const float*)d_in[8];
    const float* n_w1 = (const float*)d_in[9];
    const float* n_b1 = (const float*)d_in[10];
    const float* n_w2 = (const float*)d_in[11];
    const float* n_b2 = (const float*)d_in[12];
    const float* t_w1 = (const float*)d_in[13];
    const float* t_b1 = (const float*)d_in[14];
    const float* t_w2 = (const float*)d_in[15];
    const float* t_b2 = (const float*)d_in[16];
    float* out = (float*)d_out;

    const int N = in_sizes[0] / DIM;
    const int E = in_sizes[4];

    float* aggr    = (float*)d_ws;                    // N*128
    float* vec_sum = aggr + (size_t)N * DIM;          // N*3
    float* counts  = vec_sum + (size_t)N * 3;         // N

    hipMemsetAsync(d_ws, 0, (size_t)N * (DIM + 4) * sizeof(float), stream);

    scatter_vec_kernel<<<(E + 255) / 256, 256, 0, stream>>>(
        edge_index + E, edge_vec, vec_sum, counts, E);

    edge_kernel<<<(E + TILE - 1) / TILE, NTHREADS, 0, stream>>>(
        x, edge_index, edge_attr, edge_vec, edge_length,
        e_w1, e_b1, e_w2, e_b2, t_w1, t_b1, t_w2, t_b2,
        vec_sum, counts, aggr, E, N);

    node_kernel<<<(N + TILE - 1) / TILE, NTHREADS, 0, stream>>>(
        x, aggr, n_w1, n_b1, n_w2, n_b2, out, N);
}

// Round 4
// 1533.446 us; speedup vs baseline: 1.8262x; 1.8262x over previous
//
#include <hip/hip_runtime.h>
#include <math.h>

#define DIM 128
#define NRBF 64
#define K1 320          // dim + rbf + dim
#define ET 64           // edges per block
#define NT 64           // nodes per block

typedef __attribute__((ext_vector_type(8))) _Float16 f16x8;
typedef __attribute__((ext_vector_type(4))) float f32x4;

__device__ __forceinline__ float sigmoidf_(float v) { return 1.0f / (1.0f + __expf(-v)); }
__device__ __forceinline__ float swishf_(float v)   { return v * sigmoidf_(v); }

__device__ __forceinline__ f16x8 cvt8(float4 a, float4 b) {
    f16x8 v;
    v[0] = (_Float16)a.x; v[1] = (_Float16)a.y; v[2] = (_Float16)a.z; v[3] = (_Float16)a.w;
    v[4] = (_Float16)b.x; v[5] = (_Float16)b.y; v[6] = (_Float16)b.z; v[7] = (_Float16)b.w;
    return v;
}

// ---------------------------------------------------------------------------
// Prep: x (f32) -> f16
// ---------------------------------------------------------------------------
__global__ void cvt_x_kernel(const float* __restrict__ in, _Float16* __restrict__ out,
                             int n8) {
    int i = blockIdx.x * blockDim.x + threadIdx.x;
    if (i >= n8) return;
    const float4* p = (const float4*)in + 2 * (size_t)i;
    float4 a = p[0], b = p[1];
    ((f16x8*)out)[i] = cvt8(a, b);
}

// Prep: weight [K][128] f32 -> transposed f16 [128][K]
__global__ void wT_kernel(const float* __restrict__ w, _Float16* __restrict__ wt, int K) {
    int k = blockIdx.x * 64 + threadIdx.x;
    int n = blockIdx.y;
    if (k < K) wt[(size_t)n * K + k] = (_Float16)w[(size_t)k * DIM + n];
}

// ---------------------------------------------------------------------------
// Pass 1: scatter edge_vec sums + counts (atomics)
// ---------------------------------------------------------------------------
__global__ void scatter_vec_kernel(const int* __restrict__ col,
                                   const float* __restrict__ edge_vec,
                                   float* __restrict__ vec_sum,
                                   float* __restrict__ counts, int E) {
    int e = blockIdx.x * blockDim.x + threadIdx.x;
    if (e >= E) return;
    int c = col[e];
    atomicAdd(&vec_sum[(size_t)c * 3 + 0], edge_vec[(size_t)e * 3 + 0]);
    atomicAdd(&vec_sum[(size_t)c * 3 + 1], edge_vec[(size_t)e * 3 + 1]);
    atomicAdd(&vec_sum[(size_t)c * 3 + 2], edge_vec[(size_t)e * 3 + 2]);
    atomicAdd(&counts[c], 1.0f);
}

// ---------------------------------------------------------------------------
// Pass 2: fused edge pipeline, fp16 MFMA (fp32 accumulate).
// 512 threads = 8 waves. wave w: m16 = w>>1 (rows 16*m16..+15 of the 64-edge
// tile), nh = w&1 (cols 64*nh..+63 as 4 n-tiles of 16).
// A-frag: row=lane&15, k=8*(lane>>4)+i (contiguous 16B).
// B-frag from wT[n][k]: col=lane&15 (+16j+64nh), same k (contiguous 16B).
// C/D:   col=lane&15, row=4*(lane>>4)+reg.
// ---------------------------------------------------------------------------
__global__ __launch_bounds__(512, 4)
void edge_mfma(const _Float16* __restrict__ xb,
               const int* __restrict__ ei,
               const float* __restrict__ eattr,
               const float* __restrict__ evec,
               const float* __restrict__ elen,
               const _Float16* __restrict__ we1T, const float* __restrict__ e_b1,
               const _Float16* __restrict__ we2T, const float* __restrict__ e_b2,
               const _Float16* __restrict__ tw1T, const float* __restrict__ t_w1r,
               const float* __restrict__ t_b1,
               const _Float16* __restrict__ tw2T, const float* __restrict__ t_b2,
               const float* __restrict__ vec_sum, const float* __restrict__ counts,
               float* __restrict__ aggr, int E) {
    __shared__ _Float16 sh[ET][DIM + 8];   // activation relay, padded (272B row)
    __shared__ float s_cos[ET];
    __shared__ int s_col[ET];

    const int tid = threadIdx.x;
    const int eb = blockIdx.x * ET;
    const int wid = tid >> 6, lane = tid & 63;
    const int lr = lane & 15, lk = lane >> 4;
    const int m16 = wid >> 1, nh = wid & 1;
    const int bcol = 64 * nh + lr;               // C/B col base; +16*j per n-tile
    const int rbase = 16 * m16 + 4 * lk;         // C row base; +r

    // --- stage cos_theta + col indices (first 64 threads) ---
    if (tid < ET) {
        int e = min(eb + tid, E - 1);
        int c = ei[(size_t)E + e];
        s_col[tid] = c;
        float cnt = fmaxf(counts[c], 1.0f);
        float vx = vec_sum[(size_t)c * 3 + 0] / cnt;
        float vy = vec_sum[(size_t)c * 3 + 1] / cnt;
        float vz = vec_sum[(size_t)c * 3 + 2] / cnt;
        float ex = evec[(size_t)e * 3 + 0];
        float ey = evec[(size_t)e * 3 + 1];
        float ez = evec[(size_t)e * 3 + 2];
        float dot = ex * vx + ey * vy + ez * vz;
        float nrm = sqrtf(vx * vx + vy * vy + vz * vz);
        float ct = dot / (elen[e] * (nrm + 1e-6f));
        s_cos[tid] = fminf(1.0f, fmaxf(-1.0f, ct));
    }

    // --- per-lane A-row pointers ---
    const int erow = min(eb + 16 * m16 + lr, E - 1);
    const int xr = ei[erow], xc = ei[(size_t)E + erow];
    const _Float16* pxr = xb + (size_t)xr * DIM + 8 * lk;
    const _Float16* pxc = xb + (size_t)xc * DIM + 8 * lk;
    const float* pat = eattr + (size_t)erow * NRBF + 8 * lk;

    const f32x4 zero = {0.f, 0.f, 0.f, 0.f};

    // ---- layer 1: [64x320] @ e_w1 -> swish ----
    f32x4 acc[4] = {zero, zero, zero, zero};
#pragma unroll
    for (int kt = 0; kt < 10; ++kt) {
        f16x8 a;
        if (kt < 4) {
            a = *(const f16x8*)(pxr + 32 * kt);
        } else if (kt < 6) {
            float4 f0 = *(const float4*)(pat + 32 * (kt - 4));
            float4 f1 = *(const float4*)(pat + 32 * (kt - 4) + 4);
            a = cvt8(f0, f1);
        } else {
            a = *(const f16x8*)(pxc + 32 * (kt - 6));
        }
#pragma unroll
        for (int j = 0; j < 4; ++j) {
            f16x8 b = *(const f16x8*)(we1T + (size_t)(bcol + 16 * j) * K1 + 32 * kt + 8 * lk);
            acc[j] = __builtin_amdgcn_mfma_f32_16x16x32_f16(a, b, acc[j], 0, 0, 0);
        }
    }
#pragma unroll
    for (int j = 0; j < 4; ++j) {
        float bv = e_b1[bcol + 16 * j];
#pragma unroll
        for (int r = 0; r < 4; ++r)
            sh[rbase + r][bcol + 16 * j] = (_Float16)swishf_(acc[j][r] + bv);
    }
    __syncthreads();

    // ---- layer 2: h1 @ e_w2 -> swish = m (keep f32 in regs, f16 in LDS) ----
    f32x4 acc2[4] = {zero, zero, zero, zero};
#pragma unroll
    for (int kt = 0; kt < 4; ++kt) {
        f16x8 a = *(const f16x8*)(&sh[16 * m16 + lr][32 * kt + 8 * lk]);
#pragma unroll
        for (int j = 0; j < 4; ++j) {
            f16x8 b = *(const f16x8*)(we2T + (size_t)(bcol + 16 * j) * DIM + 32 * kt + 8 * lk);
            acc2[j] = __builtin_amdgcn_mfma_f32_16x16x32_f16(a, b, acc2[j], 0, 0, 0);
        }
    }
    __syncthreads();
    float m_[4][4];
#pragma unroll
    for (int j = 0; j < 4; ++j) {
        float bv = e_b2[bcol + 16 * j];
#pragma unroll
        for (int r = 0; r < 4; ++r) {
            float mm = swishf_(acc2[j][r] + bv);
            m_[j][r] = mm;
            sh[rbase + r][bcol + 16 * j] = (_Float16)mm;
        }
    }
    __syncthreads();

    // ---- layer 3: [m | cos] @ t_w1 -> swish ----
    f32x4 acc3[4] = {zero, zero, zero, zero};
#pragma unroll
    for (int kt = 0; kt < 4; ++kt) {
        f16x8 a = *(const f16x8*)(&sh[16 * m16 + lr][32 * kt + 8 * lk]);
#pragma unroll
        for (int j = 0; j < 4; ++j) {
            f16x8 b = *(const f16x8*)(tw1T + (size_t)(bcol + 16 * j) * DIM + 32 * kt + 8 * lk);
            acc3[j] = __builtin_amdgcn_mfma_f32_16x16x32_f16(a, b, acc3[j], 0, 0, 0);
        }
    }
    __syncthreads();
#pragma unroll
    for (int j = 0; j < 4; ++j) {
        float bv = t_b1[bcol + 16 * j];
        float wr = t_w1r[bcol + 16 * j];   // t_w1 row 128 (cos column)
#pragma unroll
        for (int r = 0; r < 4; ++r) {
            float ct = s_cos[rbase + r];
            sh[rbase + r][bcol + 16 * j] = (_Float16)swishf_(acc3[j][r] + ct * wr + bv);
        }
    }
    __syncthreads();

    // ---- layer 4: h2 @ t_w2 -> sigmoid -> gate -> atomic scatter ----
    f32x4 acc4[4] = {zero, zero, zero, zero};
#pragma unroll
    for (int kt = 0; kt < 4; ++kt) {
        f16x8 a = *(const f16x8*)(&sh[16 * m16 + lr][32 * kt + 8 * lk]);
#pragma unroll
        for (int j = 0; j < 4; ++j) {
            f16x8 b = *(const f16x8*)(tw2T + (size_t)(bcol + 16 * j) * DIM + 32 * kt + 8 * lk);
            acc4[j] = __builtin_amdgcn_mfma_f32_16x16x32_f16(a, b, acc4[j], 0, 0, 0);
        }
    }
#pragma unroll
    for (int j = 0; j < 4; ++j) {
        float bv = t_b2[bcol + 16 * j];
#pragma unroll
        for (int r = 0; r < 4; ++r) {
            int rowE = rbase + r;
            if (eb + rowE < E) {
                float g = sigmoidf_(acc4[j][r] + bv);
                atomicAdd(&aggr[(size_t)s_col[rowE] * DIM + bcol + 16 * j], m_[j][r] * g);
            }
        }
    }
}

// ---------------------------------------------------------------------------
// Pass 3: node MLP on [x | aggr] + residual, fp16 MFMA.
// ---------------------------------------------------------------------------
__global__ __launch_bounds__(512, 4)
void node_mfma(const _Float16* __restrict__ xb, const float* __restrict__ x,
               const float* __restrict__ aggr,
               const _Float16* __restrict__ nw1T, const float* __restrict__ n_b1,
               const _Float16* __restrict__ nw2T, const float* __restrict__ n_b2,
               float* __restrict__ out, int N) {
    __shared__ _Float16 sh[NT][DIM + 8];

    const int tid = threadIdx.x;
    const int nb = blockIdx.x * NT;
    const int wid = tid >> 6, lane = tid & 63;
    const int lr = lane & 15, lk = lane >> 4;
    const int m16 = wid >> 1, nh = wid & 1;
    const int bcol = 64 * nh + lr;
    const int rbase = 16 * m16 + 4 * lk;

    const int nrow = min(nb + 16 * m16 + lr, N - 1);
    const _Float16* px = xb + (size_t)nrow * DIM + 8 * lk;
    const float* pa = aggr + (size_t)nrow * DIM + 8 * lk;

    const f32x4 zero = {0.f, 0.f, 0.f, 0.f};

    // ---- layer 1: [64x256] @ n_w1 -> swish ----
    f32x4 acc[4] = {zero, zero, zero, zero};
#pragma unroll
    for (int kt = 0; kt < 8; ++kt) {
        f16x8 a;
        if (kt < 4) {
            a = *(const f16x8*)(px + 32 * kt);
        } else {
            float4 f0 = *(const float4*)(pa + 32 * (kt - 4));
            float4 f1 = *(const float4*)(pa + 32 * (kt - 4) + 4);
            a = cvt8(f0, f1);
        }
#pragma unroll
        for (int j = 0; j < 4; ++j) {
            f16x8 b = *(const f16x8*)(nw1T + (size_t)(bcol + 16 * j) * 256 + 32 * kt + 8 * lk);
            acc[j] = __builtin_amdgcn_mfma_f32_16x16x32_f16(a, b, acc[j], 0, 0, 0);
        }
    }
#pragma unroll
    for (int j = 0; j < 4; ++j) {
        float bv = n_b1[bcol + 16 * j];
#pragma unroll
        for (int r = 0; r < 4; ++r)
            sh[rbase + r][bcol + 16 * j] = (_Float16)swishf_(acc[j][r] + bv);
    }
    __syncthreads();

    // ---- layer 2: h1 @ n_w2 -> swish, + residual, store ----
    f32x4 acc2[4] = {zero, zero, zero, zero};
#pragma unroll
    for (int kt = 0; kt < 4; ++kt) {
        f16x8 a = *(const f16x8*)(&sh[16 * m16 + lr][32 * kt + 8 * lk]);
#pragma unroll
        for (int j = 0; j < 4; ++j) {
            f16x8 b = *(const f16x8*)(nw2T + (size_t)(bcol + 16 * j) * DIM + 32 * kt + 8 * lk);
            acc2[j] = __builtin_amdgcn_mfma_f32_16x16x32_f16(a, b, acc2[j], 0, 0, 0);
        }
    }
#pragma unroll
    for (int j = 0; j < 4; ++j) {
        float bv = n_b2[bcol + 16 * j];
#pragma unroll
        for (int r = 0; r < 4; ++r) {
            int row = nb + rbase + r;
            if (row < N) {
                int col = bcol + 16 * j;
                out[(size_t)row * DIM + col] =
                    x[(size_t)row * DIM + col] + swishf_(acc2[j][r] + bv);
            }
        }
    }
}

// ---------------------------------------------------------------------------
extern "C" void kernel_launch(void* const* d_in, const int* in_sizes, int n_in,
                              void* d_out, int out_size, void* d_ws, size_t ws_size,
                              hipStream_t stream) {
    const float* x           = (const float*)d_in[0];
    const int*   edge_index  = (const int*)d_in[1];
    const float* edge_attr   = (const float*)d_in[2];
    const float* edge_vec    = (const float*)d_in[3];
    const float* edge_length = (const float*)d_in[4];
    const float* e_w1 = (const float*)d_in[5];
    const float* e_b1 = (const float*)d_in[6];
    const float* e_w2 = (const float*)d_in[7];
    const float* e_b2 = (const float*)d_in[8];
    const float* n_w1 = (const float*)d_in[9];
    const float* n_b1 = (const float*)d_in[10];
    const float* n_w2 = (const float*)d_in[11];
    const float* n_b2 = (const float*)d_in[12];
    const float* t_w1 = (const float*)d_in[13];
    const float* t_b1 = (const float*)d_in[14];
    const float* t_w2 = (const float*)d_in[15];
    const float* t_b2 = (const float*)d_in[16];
    float* out = (float*)d_out;

    const int N = in_sizes[0] / DIM;
    const int E = in_sizes[4];

    // workspace layout (16B-aligned partitions)
    float* aggr    = (float*)d_ws;                       // N*128 f32
    float* vec_sum = aggr + (size_t)N * DIM;             // N*3
    float* counts  = vec_sum + (size_t)N * 3;            // N
    _Float16* xb   = (_Float16*)(counts + N);            // N*128 f16
    _Float16* we1T = xb + (size_t)N * DIM;               // 128*320
    _Float16* we2T = we1T + 128 * K1;                    // 128*128
    _Float16* tw1T = we2T + 128 * DIM;                   // 128*128
    _Float16* tw2T = tw1T + 128 * DIM;                   // 128*128
    _Float16* nw1T = tw2T + 128 * DIM;                   // 128*256
    _Float16* nw2T = nw1T + 128 * 256;                   // 128*128
    const float* t_w1r = t_w1 + (size_t)DIM * DIM;       // row 128 of t_w1

    hipMemsetAsync(d_ws, 0, (size_t)N * (DIM + 4) * sizeof(float), stream);

    // prep: conversions + transposes
    {
        int n8 = N * DIM / 8;
        cvt_x_kernel<<<(n8 + 255) / 256, 256, 0, stream>>>(x, xb, n8);
        wT_kernel<<<dim3(5, 128), 64, 0, stream>>>(e_w1, we1T, K1);
        wT_kernel<<<dim3(2, 128), 64, 0, stream>>>(e_w2, we2T, DIM);
        wT_kernel<<<dim3(2, 128), 64, 0, stream>>>(t_w1, tw1T, DIM);  // rows 0..127
        wT_kernel<<<dim3(2, 128), 64, 0, stream>>>(t_w2, tw2T, DIM);
        wT_kernel<<<dim3(4, 128), 64, 0, stream>>>(n_w1, nw1T, 256);
        wT_kernel<<<dim3(2, 128), 64, 0, stream>>>(n_w2, nw2T, DIM);
    }

    scatter_vec_kernel<<<(E + 255) / 256, 256, 0, stream>>>(
        edge_index + E, edge_vec, vec_sum, counts, E);

    edge_mfma<<<(E + ET - 1) / ET, 512, 0, stream>>>(
        xb, edge_index, edge_attr, edge_vec, edge_length,
        we1T, e_b1, we2T, e_b2, tw1T, t_w1r, t_b1, tw2T, t_b2,
        vec_sum, counts, aggr, E);

    node_mfma<<<(N + NT - 1) / NT, 512, 0, stream>>>(
        xb, x, aggr, nw1T, n_b1, nw2T, n_b2, out, N);
}